// Round 10
// baseline (334.481 us; speedup 1.0000x reference)
//
#include <hip/hip_runtime.h>

#define N_NODES 50000
#define N_EDGES 800000
#define CH 128
#define NOUT 10
#define NUM_GRAPHS 128
#define SCAN_B 256
#define N_SCAN_BLOCKS ((N_NODES + SCAN_B - 1) / SCAN_B)   // 196
#define POOL_CHUNK 50
#define GR 64                                              // gemm rows per block
#define GEMM_BLOCKS ((N_NODES + GR - 1) / GR)              // 782
#define FILL_SEGS 128
#define FILL_CHUNK (N_EDGES / FILL_SEGS)                   // 6250
#define DST_RANGE (N_NODES / 8)                            // 6250
#define XS_STRIDE 132                                      // +4 pad: conflict-free 4-row reads

// pack two fp32 -> bf16x2 dword, round-to-nearest-even
__device__ __forceinline__ unsigned pack_bf16(float a, float b) {
    unsigned ua = __float_as_uint(a), ub = __float_as_uint(b);
    ua += 0x7fffu + ((ua >> 16) & 1u);
    ub += 0x7fffu + ((ub >> 16) & 1u);
    return (ua >> 16) | (ub & 0xffff0000u);
}

__device__ __forceinline__ float4 fma4(float s, float4 w, float4 a) {
    a.x = fmaf(s, w.x, a.x); a.y = fmaf(s, w.y, a.y);
    a.z = fmaf(s, w.z, a.z); a.w = fmaf(s, w.w, a.w);
    return a;
}

// ===== GEMM v6: Y'bf16[row] = dinv[row]*(X[row]@W); thread = 4 rows x 8 cols =
__device__ __forceinline__ void gemm_body6(const float* __restrict__ X,
                                           const float* __restrict__ W,
                                           unsigned* __restrict__ Yb,
                                           const float* __restrict__ dinv,
                                           float* __restrict__ xs, int bid) {
    const int tid = threadIdx.x;
    const int cg = tid & 15;          // cols cg*8 .. cg*8+7
    const int rg = tid >> 4;          // rows rg*4 .. rg*4+3
    const int row0 = bid * GR;

    // stage 64 rows x 128 ch into padded LDS
    const float4* Xv = (const float4*)X;
    #pragma unroll
    for (int i = 0; i < 8; ++i) {
        int f = tid + i * 256;        // [0,2048)
        int r = f >> 5, c4 = f & 31;
        float4 val = make_float4(0.f, 0.f, 0.f, 0.f);
        if (row0 + r < N_NODES) val = Xv[(size_t)(row0 + r) * 32 + c4];
        *(float4*)&xs[r * XS_STRIDE + c4 * 4] = val;
    }
    __syncthreads();

    float4 acc[4][2];
    #pragma unroll
    for (int i = 0; i < 4; ++i) {
        acc[i][0] = make_float4(0.f, 0.f, 0.f, 0.f);
        acc[i][1] = make_float4(0.f, 0.f, 0.f, 0.f);
    }

    const float4* Wv = (const float4*)W;
    float4 wa[4], wb[4];
    #pragma unroll
    for (int k = 0; k < 4; ++k) {
        wa[k] = Wv[k * 32 + cg * 2];
        wb[k] = Wv[k * 32 + cg * 2 + 1];
    }

    for (int k4 = 0; k4 < CH / 4; ++k4) {
        const int nk4 = (k4 + 1) & (CH / 4 - 1);
        float4 na[4], nb[4];
        #pragma unroll
        for (int k = 0; k < 4; ++k) {              // prefetch next chunk's W
            na[k] = Wv[(nk4 * 4 + k) * 32 + cg * 2];
            nb[k] = Wv[(nk4 * 4 + k) * 32 + cg * 2 + 1];
        }
        #pragma unroll
        for (int i = 0; i < 4; ++i) {
            float4 xr = *(const float4*)&xs[(rg * 4 + i) * XS_STRIDE + k4 * 4];
            acc[i][0] = fma4(xr.x, wa[0], acc[i][0]);
            acc[i][1] = fma4(xr.x, wb[0], acc[i][1]);
            acc[i][0] = fma4(xr.y, wa[1], acc[i][0]);
            acc[i][1] = fma4(xr.y, wb[1], acc[i][1]);
            acc[i][0] = fma4(xr.z, wa[2], acc[i][0]);
            acc[i][1] = fma4(xr.z, wb[2], acc[i][1]);
            acc[i][0] = fma4(xr.w, wa[3], acc[i][0]);
            acc[i][1] = fma4(xr.w, wb[3], acc[i][1]);
        }
        #pragma unroll
        for (int k = 0; k < 4; ++k) { wa[k] = na[k]; wb[k] = nb[k]; }
    }

    #pragma unroll
    for (int i = 0; i < 4; ++i) {
        int row = row0 + rg * 4 + i;
        if (row < N_NODES) {
            float dv = dinv[row];      // 16-lane broadcast
            uint4 p;
            p.x = pack_bf16(acc[i][0].x * dv, acc[i][0].y * dv);
            p.y = pack_bf16(acc[i][0].z * dv, acc[i][0].w * dv);
            p.z = pack_bf16(acc[i][1].x * dv, acc[i][1].y * dv);
            p.w = pack_bf16(acc[i][1].z * dv, acc[i][1].w * dv);
            ((uint4*)Yb)[(size_t)row * 16 + cg] = p;
        }
    }
}

__global__ __launch_bounds__(256, 3) void k_gemm6(const float* __restrict__ X,
                                                  const float* __restrict__ W,
                                                  unsigned* __restrict__ Yb,
                                                  const float* __restrict__ dinv) {
    __shared__ float xs[GR * XS_STRIDE];
    gemm_body6(X, W, Yb, dinv, xs, blockIdx.x);
}

// conv2 GEMM also zeroes psum (pool runs after)
__global__ __launch_bounds__(256, 3) void k_gemm6b(const float* __restrict__ X,
                                                   const float* __restrict__ W,
                                                   unsigned* __restrict__ Yb,
                                                   const float* __restrict__ dinv,
                                                   float* __restrict__ psum) {
    if (blockIdx.x < 64) psum[blockIdx.x * 256 + threadIdx.x] = 0.f;
    __shared__ float xs[GR * XS_STRIDE];
    gemm_body6(X, W, Yb, dinv, xs, blockIdx.x);
}

// ============ XCD-partitioned hist ============
__global__ __launch_bounds__(256) void k_hist_x(const int* __restrict__ dst,
                                                int* __restrict__ cnt) {
    const int xcd = blockIdx.x & 7;
    const int seg = blockIdx.x >> 3;
    const int lo = xcd * DST_RANGE, hi = lo + DST_RANGE;
    const int base = seg * FILL_CHUNK;
    for (int it = 0; it < FILL_CHUNK; it += 256) {
        int e = base + it + threadIdx.x;
        if (it + (int)threadIdx.x < FILL_CHUNK) {
            int d = dst[e];
            if (d >= lo && d < hi) atomicAdd(&cnt[d], 1);
        }
    }
}

// ================= scans =================
__global__ __launch_bounds__(SCAN_B) void k_scan1(const int* __restrict__ cnt,
                                                  int* __restrict__ row_start,
                                                  int* __restrict__ bsum) {
    __shared__ int s[SCAN_B];
    int tid = threadIdx.x;
    int i = blockIdx.x * SCAN_B + tid;
    int v = (i < N_NODES) ? cnt[i] : 0;
    s[tid] = v;
    __syncthreads();
    for (int off = 1; off < SCAN_B; off <<= 1) {
        int t = (tid >= off) ? s[tid - off] : 0;
        __syncthreads();
        s[tid] += t;
        __syncthreads();
    }
    if (i < N_NODES) row_start[i] = s[tid] - v;
    if (tid == SCAN_B - 1) bsum[blockIdx.x] = s[tid];
}

__global__ __launch_bounds__(SCAN_B) void k_scan2(int* __restrict__ bsum) {
    __shared__ int s[SCAN_B];
    int tid = threadIdx.x;
    int v = (tid < N_SCAN_BLOCKS) ? bsum[tid] : 0;
    s[tid] = v;
    __syncthreads();
    for (int off = 1; off < SCAN_B; off <<= 1) {
        int t = (tid >= off) ? s[tid - off] : 0;
        __syncthreads();
        s[tid] += t;
        __syncthreads();
    }
    if (tid < N_SCAN_BLOCKS) bsum[tid] = s[tid] - v;
}

__global__ __launch_bounds__(SCAN_B) void k_scan3(int* __restrict__ row_start,
                                                  const int* __restrict__ bsum,
                                                  int* __restrict__ fill_pos,
                                                  const int* __restrict__ cnt,
                                                  float* __restrict__ dinv) {
    int i = blockIdx.x * SCAN_B + threadIdx.x;
    if (i < N_NODES) {
        int rs = row_start[i] + bsum[blockIdx.x];
        row_start[i] = rs;
        fill_pos[i] = rs;
        dinv[i] = rsqrtf((float)(cnt[i] + 1));
    }
}

// ============ XCD-partitioned fill ============
__global__ __launch_bounds__(256) void k_fill_x(const int* __restrict__ src,
                                                const int* __restrict__ dst,
                                                int* __restrict__ fill_pos,
                                                int* __restrict__ csr_src) {
    const int xcd = blockIdx.x & 7;
    const int seg = blockIdx.x >> 3;
    const int lo = xcd * DST_RANGE, hi = lo + DST_RANGE;
    const int base = seg * FILL_CHUNK;
    for (int it = 0; it < FILL_CHUNK; it += 256) {
        int e = base + it + threadIdx.x;
        if (it + (int)threadIdx.x < FILL_CHUNK) {
            int d = dst[e];
            if (d >= lo && d < hi) {
                int s = src[e];
                int pos = atomicAdd(&fill_pos[d], 1);
                csr_src[pos] = s;
            }
        }
    }
}

// ===== gather over bf16 t' rows: h[v] = relu(dv*(sum t'[u] + t'[v]) + b) ====
__global__ __launch_bounds__(256) void k_gather_bf(const unsigned* __restrict__ tb,
                                                   const int* __restrict__ csr_src,
                                                   const int* __restrict__ row_start,
                                                   const int* __restrict__ cnt,
                                                   const float* __restrict__ dinv,
                                                   const float* __restrict__ b,
                                                   float* __restrict__ h) {
    const int wid = threadIdx.x >> 6;
    const int lane = threadIdx.x & 63;
    const int v = blockIdx.x * 4 + wid;      // 12500 * 4 = 50000 exactly

    const int start = row_start[v];
    const int len = cnt[v];
    const float dv = dinv[v];

    float x0 = 0.f, y0 = 0.f, x1 = 0.f, y1 = 0.f;
    float x2 = 0.f, y2 = 0.f, x3 = 0.f, y3 = 0.f;

    for (int base = 0; base < len; base += 64) {
        int m = len - base; if (m > 64) m = 64;
        int u_l = 0;
        if (lane < m) u_l = csr_src[start + base + lane];   // coalesced
        int j = 0;
        for (; j + 3 < m; j += 4) {
            int u0 = __shfl(u_l, j),     u1 = __shfl(u_l, j + 1);
            int u2 = __shfl(u_l, j + 2), u3 = __shfl(u_l, j + 3);
            unsigned r0 = tb[(size_t)u0 * 64 + lane];   // 256B/row coalesced
            unsigned r1 = tb[(size_t)u1 * 64 + lane];
            unsigned r2 = tb[(size_t)u2 * 64 + lane];
            unsigned r3 = tb[(size_t)u3 * 64 + lane];
            x0 += __uint_as_float(r0 << 16); y0 += __uint_as_float(r0 & 0xffff0000u);
            x1 += __uint_as_float(r1 << 16); y1 += __uint_as_float(r1 & 0xffff0000u);
            x2 += __uint_as_float(r2 << 16); y2 += __uint_as_float(r2 & 0xffff0000u);
            x3 += __uint_as_float(r3 << 16); y3 += __uint_as_float(r3 & 0xffff0000u);
        }
        for (; j < m; ++j) {
            int u = __shfl(u_l, j);
            unsigned r = tb[(size_t)u * 64 + lane];
            x0 += __uint_as_float(r << 16); y0 += __uint_as_float(r & 0xffff0000u);
        }
    }

    unsigned rs = tb[(size_t)v * 64 + lane];   // self term t'[v]
    float sx = x0 + x1 + x2 + x3 + __uint_as_float(rs << 16);
    float sy = y0 + y1 + y2 + y3 + __uint_as_float(rs & 0xffff0000u);
    float2 bb = ((const float2*)b)[lane];
    float2 o;
    o.x = fmaxf(fmaf(dv, sx, bb.x), 0.f);
    o.y = fmaxf(fmaf(dv, sy, bb.y), 0.f);
    ((float2*)h)[(size_t)v * 64 + lane] = o;
}

// ================= segmented mean pool (batch sorted) =================
__global__ __launch_bounds__(128) void k_pool2(const float* __restrict__ h,
                                               const int* __restrict__ batch,
                                               float* __restrict__ psum) {
    const int c = threadIdx.x;
    const int v0 = blockIdx.x * POOL_CHUNK;
    __shared__ int bg[POOL_CHUNK];
    if (c < POOL_CHUNK) bg[c] = batch[v0 + c];
    __syncthreads();

    float acc = 0.f;
    int g = bg[0];
    #pragma unroll 5
    for (int j = 0; j < POOL_CHUNK; ++j) {
        int bgj = bg[j];
        float val = h[(size_t)(v0 + j) * CH + c];
        if (bgj != g) {
            atomicAdd(&psum[g * CH + c], acc);
            acc = 0.f;
            g = bgj;
        }
        acc += val;
    }
    atomicAdd(&psum[g * CH + c], acc);
}

// ================= classifier head (count via binary search) =================
__global__ __launch_bounds__(128) void k_classify(const float* __restrict__ psum,
                                                  const int* __restrict__ batch,
                                                  const float* __restrict__ Wc,
                                                  const float* __restrict__ bc,
                                                  float* __restrict__ out) {
    __shared__ float p[CH];
    __shared__ float sinv;
    int g = blockIdx.x;
    int tid = threadIdx.x;
    if (tid == 0) {
        int lo = 0, hi = N_NODES;
        while (lo < hi) { int mid = (lo + hi) >> 1; if (batch[mid] < g) lo = mid + 1; else hi = mid; }
        int start = lo;
        lo = 0; hi = N_NODES;
        while (lo < hi) { int mid = (lo + hi) >> 1; if (batch[mid] < g + 1) lo = mid + 1; else hi = mid; }
        sinv = 1.0f / fmaxf((float)(lo - start), 1.0f);
    }
    __syncthreads();
    p[tid] = psum[g * CH + tid] * sinv;
    __syncthreads();
    if (tid < NOUT) {
        float acc = bc[tid];
        #pragma unroll 4
        for (int k = 0; k < CH; ++k) acc += p[k] * Wc[k * NOUT + tid];
        out[g * NOUT + tid] = acc;
    }
}

extern "C" void kernel_launch(void* const* d_in, const int* in_sizes, int n_in,
                              void* d_out, int out_size, void* d_ws, size_t ws_size,
                              hipStream_t stream) {
    const float* x     = (const float*)d_in[0];
    const int*   ei    = (const int*)d_in[1];
    const int*   batch = (const int*)d_in[2];
    const float* W1    = (const float*)d_in[3];
    const float* b1    = (const float*)d_in[4];
    const float* W2    = (const float*)d_in[5];
    const float* b2    = (const float*)d_in[6];
    const float* Wc    = (const float*)d_in[7];
    const float* bc    = (const float*)d_in[8];
    float* out = (float*)d_out;

    const int* src = ei;
    const int* dst = ei + N_EDGES;

    float*    dinv      = (float*)d_ws;                    // N
    int*      cnt       = (int*)(dinv + N_NODES);          // N
    int*      row_start = cnt + N_NODES;                   // N
    int*      fill_pos  = row_start + N_NODES;             // N
    int*      bsum      = fill_pos + N_NODES;              // 256
    int*      csr_src   = bsum + 256;                      // E
    unsigned* tb        = (unsigned*)(csr_src + N_EDGES);  // N*64 dwords (bf16 t')
    float*    hbuf      = (float*)(tb + (size_t)N_NODES * 64);  // N*CH
    float*    psum      = hbuf + (size_t)N_NODES * CH;     // G*CH

    // ---- CSR build + dinv (must precede GEMM: epilogue scales by dinv) ----
    hipMemsetAsync(cnt, 0, N_NODES * sizeof(int), stream);
    k_hist_x<<<FILL_SEGS * 8, 256, 0, stream>>>(dst, cnt);
    k_scan1<<<N_SCAN_BLOCKS, SCAN_B, 0, stream>>>(cnt, row_start, bsum);
    k_scan2<<<1, SCAN_B, 0, stream>>>(bsum);
    k_scan3<<<N_SCAN_BLOCKS, SCAN_B, 0, stream>>>(row_start, bsum, fill_pos, cnt, dinv);
    k_fill_x<<<FILL_SEGS * 8, 256, 0, stream>>>(src, dst, fill_pos, csr_src);

    // ---- conv1 ----
    k_gemm6<<<GEMM_BLOCKS, 256, 0, stream>>>(x, W1, tb, dinv);
    k_gather_bf<<<N_NODES / 4, 256, 0, stream>>>(tb, csr_src, row_start, cnt, dinv, b1, hbuf);

    // ---- conv2 (GEMM also zeroes psum) ----
    k_gemm6b<<<GEMM_BLOCKS, 256, 0, stream>>>(hbuf, W2, tb, dinv, psum);
    k_gather_bf<<<N_NODES / 4, 256, 0, stream>>>(tb, csr_src, row_start, cnt, dinv, b2, hbuf);

    // ---- pool + head ----
    k_pool2<<<N_NODES / POOL_CHUNK, 128, 0, stream>>>(hbuf, batch, psum);
    k_classify<<<NUM_GRAPHS, 128, 0, stream>>>(psum, batch, Wc, bc, out);
}

// Round 11
// 331.953 us; speedup vs baseline: 1.0076x; 1.0076x over previous
//
#include <hip/hip_runtime.h>

#define N_NODES 50000
#define N_EDGES 800000
#define CH 128
#define NOUT 10
#define NUM_GRAPHS 128
#define SCAN_B 256
#define N_SCAN_BLOCKS ((N_NODES + SCAN_B - 1) / SCAN_B)   // 196
#define POOL_CHUNK 50
#define GR 64                                              // gemm rows per block
#define GEMM_BLOCKS ((N_NODES + GR - 1) / GR)              // 782
#define FILL_SEGS 128
#define FILL_CHUNK (N_EDGES / FILL_SEGS)                   // 6250
#define DST_RANGE (N_NODES / 8)                            // 6250

// pack two fp32 -> bf16x2 dword, round-to-nearest-even
__device__ __forceinline__ unsigned pack_bf16(float a, float b) {
    unsigned ua = __float_as_uint(a), ub = __float_as_uint(b);
    ua += 0x7fffu + ((ua >> 16) & 1u);
    ub += 0x7fffu + ((ub >> 16) & 1u);
    return (ua >> 16) | (ub & 0xffff0000u);
}

__device__ __forceinline__ float4 fma4(float s, float4 w, float4 a) {
    a.x = fmaf(s, w.x, a.x); a.y = fmaf(s, w.y, a.y);
    a.z = fmaf(s, w.z, a.z); a.w = fmaf(s, w.w, a.w);
    return a;
}

// ===== GEMM v7: thread = 8 rows x 8 cols; 128 thr = 64 rows x 128 cols ======
// acc = 64 VGPRs forces the allocator to keep W live (no sink-to-52 regress).
// xs uses XOR swizzle (c4 ^ (rg&3)) so the wave's 4 simultaneous row-reads
// (rows 8 apart -> same bank without swizzle) hit disjoint bank quads.
__device__ __forceinline__ void gemm_body7(const float* __restrict__ X,
                                           const float* __restrict__ W,
                                           unsigned* __restrict__ Yb,
                                           const float* __restrict__ dinv,
                                           float* __restrict__ xs, int bid) {
    const int tid = threadIdx.x;       // 0..127
    const int cg = tid & 15;           // cols cg*8 .. cg*8+7
    const int rg = tid >> 4;           // 0..7: rows rg*8 .. rg*8+7
    const int row0 = bid * GR;

    // stage 64 rows x 128 ch, swizzled: float4 (r, c4) -> xs[r*128 + (c4^gsw(r))*4]
    const float4* Xv = (const float4*)X;
    #pragma unroll
    for (int i = 0; i < 16; ++i) {
        int f = tid + i * 128;         // [0,2048)
        int r = f >> 5, c4 = f & 31;
        float4 val = make_float4(0.f, 0.f, 0.f, 0.f);
        if (row0 + r < N_NODES) val = Xv[(size_t)(row0 + r) * 32 + c4];
        int gsw = (r >> 3) & 3;
        *(float4*)&xs[r * 128 + ((c4 ^ gsw) << 2)] = val;
    }
    __syncthreads();

    float4 acc[8][2];
    #pragma unroll
    for (int i = 0; i < 8; ++i) {
        acc[i][0] = make_float4(0.f, 0.f, 0.f, 0.f);
        acc[i][1] = make_float4(0.f, 0.f, 0.f, 0.f);
    }

    const float4* Wv = (const float4*)W;
    const int gsw = rg & 3;            // uniform per thread
    float4 wa[4], wb[4];
    #pragma unroll
    for (int k = 0; k < 4; ++k) {
        wa[k] = Wv[k * 32 + cg * 2];
        wb[k] = Wv[k * 32 + cg * 2 + 1];
    }

    for (int k4 = 0; k4 < CH / 4; ++k4) {
        const int nk4 = (k4 + 1) & (CH / 4 - 1);
        float4 na[4], nb[4];
        #pragma unroll
        for (int k = 0; k < 4; ++k) {              // prefetch next k-chunk of W
            na[k] = Wv[(nk4 * 4 + k) * 32 + cg * 2];
            nb[k] = Wv[(nk4 * 4 + k) * 32 + cg * 2 + 1];
        }
        const int koff = ((k4 ^ gsw) << 2);
        #pragma unroll
        for (int i = 0; i < 8; ++i) {
            float4 xr = *(const float4*)&xs[(rg * 8 + i) * 128 + koff];
            acc[i][0] = fma4(xr.x, wa[0], acc[i][0]);
            acc[i][1] = fma4(xr.x, wb[0], acc[i][1]);
            acc[i][0] = fma4(xr.y, wa[1], acc[i][0]);
            acc[i][1] = fma4(xr.y, wb[1], acc[i][1]);
            acc[i][0] = fma4(xr.z, wa[2], acc[i][0]);
            acc[i][1] = fma4(xr.z, wb[2], acc[i][1]);
            acc[i][0] = fma4(xr.w, wa[3], acc[i][0]);
            acc[i][1] = fma4(xr.w, wb[3], acc[i][1]);
        }
        #pragma unroll
        for (int k = 0; k < 4; ++k) { wa[k] = na[k]; wb[k] = nb[k]; }
    }

    #pragma unroll
    for (int i = 0; i < 8; ++i) {
        int row = row0 + rg * 8 + i;
        if (row < N_NODES) {
            float dv = dinv[row];      // 16-lane broadcast
            uint4 p;
            p.x = pack_bf16(acc[i][0].x * dv, acc[i][0].y * dv);
            p.y = pack_bf16(acc[i][0].z * dv, acc[i][0].w * dv);
            p.z = pack_bf16(acc[i][1].x * dv, acc[i][1].y * dv);
            p.w = pack_bf16(acc[i][1].z * dv, acc[i][1].w * dv);
            ((uint4*)Yb)[(size_t)row * 16 + cg] = p;
        }
    }
}

__global__ __launch_bounds__(128, 2) void k_gemm7(const float* __restrict__ X,
                                                  const float* __restrict__ W,
                                                  unsigned* __restrict__ Yb,
                                                  const float* __restrict__ dinv) {
    __shared__ float xs[GR * CH];
    gemm_body7(X, W, Yb, dinv, xs, blockIdx.x);
}

// conv2 GEMM also zeroes psum (pool runs after)
__global__ __launch_bounds__(128, 2) void k_gemm7b(const float* __restrict__ X,
                                                   const float* __restrict__ W,
                                                   unsigned* __restrict__ Yb,
                                                   const float* __restrict__ dinv,
                                                   float* __restrict__ psum) {
    if (blockIdx.x < 128) psum[blockIdx.x * 128 + threadIdx.x] = 0.f;
    __shared__ float xs[GR * CH];
    gemm_body7(X, W, Yb, dinv, xs, blockIdx.x);
}

// ============ XCD-partitioned hist ============
__global__ __launch_bounds__(256) void k_hist_x(const int* __restrict__ dst,
                                                int* __restrict__ cnt) {
    const int xcd = blockIdx.x & 7;
    const int seg = blockIdx.x >> 3;
    const int lo = xcd * DST_RANGE, hi = lo + DST_RANGE;
    const int base = seg * FILL_CHUNK;
    for (int it = 0; it < FILL_CHUNK; it += 256) {
        int e = base + it + threadIdx.x;
        if (it + (int)threadIdx.x < FILL_CHUNK) {
            int d = dst[e];
            if (d >= lo && d < hi) atomicAdd(&cnt[d], 1);
        }
    }
}

// ================= scans =================
__global__ __launch_bounds__(SCAN_B) void k_scan1(const int* __restrict__ cnt,
                                                  int* __restrict__ row_start,
                                                  int* __restrict__ bsum) {
    __shared__ int s[SCAN_B];
    int tid = threadIdx.x;
    int i = blockIdx.x * SCAN_B + tid;
    int v = (i < N_NODES) ? cnt[i] : 0;
    s[tid] = v;
    __syncthreads();
    for (int off = 1; off < SCAN_B; off <<= 1) {
        int t = (tid >= off) ? s[tid - off] : 0;
        __syncthreads();
        s[tid] += t;
        __syncthreads();
    }
    if (i < N_NODES) row_start[i] = s[tid] - v;
    if (tid == SCAN_B - 1) bsum[blockIdx.x] = s[tid];
}

__global__ __launch_bounds__(SCAN_B) void k_scan2(int* __restrict__ bsum) {
    __shared__ int s[SCAN_B];
    int tid = threadIdx.x;
    int v = (tid < N_SCAN_BLOCKS) ? bsum[tid] : 0;
    s[tid] = v;
    __syncthreads();
    for (int off = 1; off < SCAN_B; off <<= 1) {
        int t = (tid >= off) ? s[tid - off] : 0;
        __syncthreads();
        s[tid] += t;
        __syncthreads();
    }
    if (tid < N_SCAN_BLOCKS) bsum[tid] = s[tid] - v;
}

__global__ __launch_bounds__(SCAN_B) void k_scan3(int* __restrict__ row_start,
                                                  const int* __restrict__ bsum,
                                                  int* __restrict__ fill_pos,
                                                  const int* __restrict__ cnt,
                                                  float* __restrict__ dinv) {
    int i = blockIdx.x * SCAN_B + threadIdx.x;
    if (i < N_NODES) {
        int rs = row_start[i] + bsum[blockIdx.x];
        row_start[i] = rs;
        fill_pos[i] = rs;
        dinv[i] = rsqrtf((float)(cnt[i] + 1));
    }
}

// ============ XCD-partitioned fill ============
__global__ __launch_bounds__(256) void k_fill_x(const int* __restrict__ src,
                                                const int* __restrict__ dst,
                                                int* __restrict__ fill_pos,
                                                int* __restrict__ csr_src) {
    const int xcd = blockIdx.x & 7;
    const int seg = blockIdx.x >> 3;
    const int lo = xcd * DST_RANGE, hi = lo + DST_RANGE;
    const int base = seg * FILL_CHUNK;
    for (int it = 0; it < FILL_CHUNK; it += 256) {
        int e = base + it + threadIdx.x;
        if (it + (int)threadIdx.x < FILL_CHUNK) {
            int d = dst[e];
            if (d >= lo && d < hi) {
                int s = src[e];
                int pos = atomicAdd(&fill_pos[d], 1);
                csr_src[pos] = s;
            }
        }
    }
}

// ===== gather over bf16 t' rows: h[v] = relu(dv*(sum t'[u] + t'[v]) + b) ====
__global__ __launch_bounds__(256) void k_gather_bf(const unsigned* __restrict__ tb,
                                                   const int* __restrict__ csr_src,
                                                   const int* __restrict__ row_start,
                                                   const int* __restrict__ cnt,
                                                   const float* __restrict__ dinv,
                                                   const float* __restrict__ b,
                                                   float* __restrict__ h) {
    const int wid = threadIdx.x >> 6;
    const int lane = threadIdx.x & 63;
    const int v = blockIdx.x * 4 + wid;      // 12500 * 4 = 50000 exactly

    const int start = row_start[v];
    const int len = cnt[v];
    const float dv = dinv[v];

    float x0 = 0.f, y0 = 0.f, x1 = 0.f, y1 = 0.f;
    float x2 = 0.f, y2 = 0.f, x3 = 0.f, y3 = 0.f;

    for (int base = 0; base < len; base += 64) {
        int m = len - base; if (m > 64) m = 64;
        int u_l = 0;
        if (lane < m) u_l = csr_src[start + base + lane];   // coalesced
        int j = 0;
        for (; j + 3 < m; j += 4) {
            int u0 = __shfl(u_l, j),     u1 = __shfl(u_l, j + 1);
            int u2 = __shfl(u_l, j + 2), u3 = __shfl(u_l, j + 3);
            unsigned r0 = tb[(size_t)u0 * 64 + lane];   // 256B/row coalesced
            unsigned r1 = tb[(size_t)u1 * 64 + lane];
            unsigned r2 = tb[(size_t)u2 * 64 + lane];
            unsigned r3 = tb[(size_t)u3 * 64 + lane];
            x0 += __uint_as_float(r0 << 16); y0 += __uint_as_float(r0 & 0xffff0000u);
            x1 += __uint_as_float(r1 << 16); y1 += __uint_as_float(r1 & 0xffff0000u);
            x2 += __uint_as_float(r2 << 16); y2 += __uint_as_float(r2 & 0xffff0000u);
            x3 += __uint_as_float(r3 << 16); y3 += __uint_as_float(r3 & 0xffff0000u);
        }
        for (; j < m; ++j) {
            int u = __shfl(u_l, j);
            unsigned r = tb[(size_t)u * 64 + lane];
            x0 += __uint_as_float(r << 16); y0 += __uint_as_float(r & 0xffff0000u);
        }
    }

    unsigned rs = tb[(size_t)v * 64 + lane];   // self term t'[v]
    float sx = x0 + x1 + x2 + x3 + __uint_as_float(rs << 16);
    float sy = y0 + y1 + y2 + y3 + __uint_as_float(rs & 0xffff0000u);
    float2 bb = ((const float2*)b)[lane];
    float2 o;
    o.x = fmaxf(fmaf(dv, sx, bb.x), 0.f);
    o.y = fmaxf(fmaf(dv, sy, bb.y), 0.f);
    ((float2*)h)[(size_t)v * 64 + lane] = o;
}

// ================= segmented mean pool (batch sorted) =================
__global__ __launch_bounds__(128) void k_pool2(const float* __restrict__ h,
                                               const int* __restrict__ batch,
                                               float* __restrict__ psum) {
    const int c = threadIdx.x;
    const int v0 = blockIdx.x * POOL_CHUNK;
    __shared__ int bg[POOL_CHUNK];
    if (c < POOL_CHUNK) bg[c] = batch[v0 + c];
    __syncthreads();

    float acc = 0.f;
    int g = bg[0];
    #pragma unroll 5
    for (int j = 0; j < POOL_CHUNK; ++j) {
        int bgj = bg[j];
        float val = h[(size_t)(v0 + j) * CH + c];
        if (bgj != g) {
            atomicAdd(&psum[g * CH + c], acc);
            acc = 0.f;
            g = bgj;
        }
        acc += val;
    }
    atomicAdd(&psum[g * CH + c], acc);
}

// ================= classifier head (count via binary search) =================
__global__ __launch_bounds__(128) void k_classify(const float* __restrict__ psum,
                                                  const int* __restrict__ batch,
                                                  const float* __restrict__ Wc,
                                                  const float* __restrict__ bc,
                                                  float* __restrict__ out) {
    __shared__ float p[CH];
    __shared__ float sinv;
    int g = blockIdx.x;
    int tid = threadIdx.x;
    if (tid == 0) {
        int lo = 0, hi = N_NODES;
        while (lo < hi) { int mid = (lo + hi) >> 1; if (batch[mid] < g) lo = mid + 1; else hi = mid; }
        int start = lo;
        lo = 0; hi = N_NODES;
        while (lo < hi) { int mid = (lo + hi) >> 1; if (batch[mid] < g + 1) lo = mid + 1; else hi = mid; }
        sinv = 1.0f / fmaxf((float)(lo - start), 1.0f);
    }
    __syncthreads();
    p[tid] = psum[g * CH + tid] * sinv;
    __syncthreads();
    if (tid < NOUT) {
        float acc = bc[tid];
        #pragma unroll 4
        for (int k = 0; k < CH; ++k) acc += p[k] * Wc[k * NOUT + tid];
        out[g * NOUT + tid] = acc;
    }
}

extern "C" void kernel_launch(void* const* d_in, const int* in_sizes, int n_in,
                              void* d_out, int out_size, void* d_ws, size_t ws_size,
                              hipStream_t stream) {
    const float* x     = (const float*)d_in[0];
    const int*   ei    = (const int*)d_in[1];
    const int*   batch = (const int*)d_in[2];
    const float* W1    = (const float*)d_in[3];
    const float* b1    = (const float*)d_in[4];
    const float* W2    = (const float*)d_in[5];
    const float* b2    = (const float*)d_in[6];
    const float* Wc    = (const float*)d_in[7];
    const float* bc    = (const float*)d_in[8];
    float* out = (float*)d_out;

    const int* src = ei;
    const int* dst = ei + N_EDGES;

    float*    dinv      = (float*)d_ws;                    // N
    int*      cnt       = (int*)(dinv + N_NODES);          // N
    int*      row_start = cnt + N_NODES;                   // N
    int*      fill_pos  = row_start + N_NODES;             // N
    int*      bsum      = fill_pos + N_NODES;              // 256
    int*      csr_src   = bsum + 256;                      // E
    unsigned* tb        = (unsigned*)(csr_src + N_EDGES);  // N*64 dwords (bf16 t')
    float*    hbuf      = (float*)(tb + (size_t)N_NODES * 64);  // N*CH
    float*    psum      = hbuf + (size_t)N_NODES * CH;     // G*CH

    // ---- CSR build + dinv (must precede GEMM: epilogue scales by dinv) ----
    hipMemsetAsync(cnt, 0, N_NODES * sizeof(int), stream);
    k_hist_x<<<FILL_SEGS * 8, 256, 0, stream>>>(dst, cnt);
    k_scan1<<<N_SCAN_BLOCKS, SCAN_B, 0, stream>>>(cnt, row_start, bsum);
    k_scan2<<<1, SCAN_B, 0, stream>>>(bsum);
    k_scan3<<<N_SCAN_BLOCKS, SCAN_B, 0, stream>>>(row_start, bsum, fill_pos, cnt, dinv);
    k_fill_x<<<FILL_SEGS * 8, 256, 0, stream>>>(src, dst, fill_pos, csr_src);

    // ---- conv1 ----
    k_gemm7<<<GEMM_BLOCKS, 128, 0, stream>>>(x, W1, tb, dinv);
    k_gather_bf<<<N_NODES / 4, 256, 0, stream>>>(tb, csr_src, row_start, cnt, dinv, b1, hbuf);

    // ---- conv2 (GEMM also zeroes psum) ----
    k_gemm7b<<<GEMM_BLOCKS, 128, 0, stream>>>(hbuf, W2, tb, dinv, psum);
    k_gather_bf<<<N_NODES / 4, 256, 0, stream>>>(tb, csr_src, row_start, cnt, dinv, b2, hbuf);

    // ---- pool + head ----
    k_pool2<<<N_NODES / POOL_CHUNK, 128, 0, stream>>>(hbuf, batch, psum);
    k_classify<<<NUM_GRAPHS, 128, 0, stream>>>(psum, batch, Wc, bc, out);
}